// Round 20
// baseline (411.500 us; speedup 1.0000x reference)
//
#include <hip/hip_runtime.h>
#include <hip/hip_bf16.h>
#include <math.h>

#define BB 2
#define NN 192
#define DD 256
#define HH 8
#define DHH 32
#define SCALE 0.17677669529663687f  // 1/sqrt(32)
#define SJ 4                         // j-splits (fallback path)
#define NS3 3                        // j-splits (fused path: 3 tiles of 64)
#define NTILE3 (BB * NN * 3)         // 1152 edge tiles of 64 rows

typedef __attribute__((ext_vector_type(8))) short short8;
typedef __attribute__((ext_vector_type(4))) float f32x4;

// ---------- helpers ----------

__device__ __forceinline__ float red32(float v) {
    v += __shfl_xor(v, 16);
    v += __shfl_xor(v, 8);
    v += __shfl_xor(v, 4);
    v += __shfl_xor(v, 2);
    v += __shfl_xor(v, 1);
    return v;
}

__device__ __forceinline__ float red64(float v) {
    v += __shfl_xor(v, 32);
    v += __shfl_xor(v, 16);
    v += __shfl_xor(v, 8);
    v += __shfl_xor(v, 4);
    v += __shfl_xor(v, 2);
    v += __shfl_xor(v, 1);
    return v;
}

__device__ __forceinline__ unsigned short f2bf(float f) {
    unsigned int u = __builtin_bit_cast(unsigned int, f);
    u += 0x7FFFu + ((u >> 16) & 1u);   // RNE
    return (unsigned short)(u >> 16);
}

__device__ __forceinline__ float bf2f(unsigned short u) {
    unsigned int v = ((unsigned int)u) << 16;
    return __builtin_bit_cast(float, v);
}

// LayerNorm 8 rows of [256] in-place in LDS. 256 threads.
__device__ __forceinline__ void ln8(float (*xs)[DD], const float* __restrict__ g,
                                    const float* __restrict__ b,
                                    float* mred, float* rred) {
    int t = threadIdx.x;
    int r = t >> 5, l = t & 31;
    float s = 0.f, s2 = 0.f;
#pragma unroll
    for (int u = 0; u < 8; u++) {
        float v = xs[r][l + 32 * u];
        s += v; s2 += v * v;
    }
    s = red32(s); s2 = red32(s2);
    if (l == 0) {
        float mean = s * (1.f / 256.f);
        float var  = s2 * (1.f / 256.f) - mean * mean;
        mred[r] = mean;
        rred[r] = rsqrtf(var + 1e-5f);
    }
    __syncthreads();
    float gt = g[t], bt = b[t];
#pragma unroll
    for (int rr = 0; rr < 8; rr++) {
        float v = xs[rr][t];
        xs[rr][t] = (v - mred[rr]) * rred[rr] * gt + bt;
    }
    __syncthreads();
}

// 256-col MFMA GEMM over a 64-row A-tile; each wave owns 32 output cols
// (2 tiles of 16), 4 m-tiles. Wf fragment-linear: tile id = w*2+nt (0..15).
// s_setprio(1) around the MFMA-dense loop (T5: role-diverse wave arbitration).
__device__ __forceinline__ void gemm256m4(const unsigned short (*A)[264],
                                          const unsigned short* __restrict__ Wf,
                                          int w, int lane, int fr, int fq,
                                          f32x4 acc[4][2]) {
#pragma unroll
    for (int m = 0; m < 4; m++)
#pragma unroll
        for (int nt = 0; nt < 2; nt++) acc[m][nt] = (f32x4){0.f, 0.f, 0.f, 0.f};
    short8 nb[2];
#pragma unroll
    for (int nt = 0; nt < 2; nt++)
        nb[nt] = *(const short8*)(Wf + (((size_t)(w * 2 + nt) * 8 + 0) * 64 + lane) * 8);
    __builtin_amdgcn_s_setprio(1);
#pragma unroll
    for (int k = 0; k < 8; k++) {
        short8 cb[2];
#pragma unroll
        for (int nt = 0; nt < 2; nt++) cb[nt] = nb[nt];
        if (k < 7) {
#pragma unroll
            for (int nt = 0; nt < 2; nt++)
                nb[nt] = *(const short8*)(Wf + (((size_t)(w * 2 + nt) * 8 + k + 1) * 64 + lane) * 8);
        }
        short8 av[4];
#pragma unroll
        for (int m = 0; m < 4; m++)
            av[m] = *(const short8*)&A[m * 16 + fr][k * 32 + fq * 8];
#pragma unroll
        for (int nt = 0; nt < 2; nt++)
#pragma unroll
            for (int m = 0; m < 4; m++)
                acc[m][nt] = __builtin_amdgcn_mfma_f32_16x16x32_bf16(av[m], cb[nt], acc[m][nt], 0, 0, 0);
    }
    __builtin_amdgcn_s_setprio(0);
}

// ---------- kernel 1 (MERGED): node prep (blocks 0..47) + weight convert (48..431) ----------
__global__ void k_prep_cvt(const float* __restrict__ x,
                           const float* __restrict__ lnxg, const float* __restrict__ lnxb,
                           const float* __restrict__ Wq, const float* __restrict__ bq,
                           const float* __restrict__ Wk, const float* __restrict__ bk,
                           const float* __restrict__ Wv, const float* __restrict__ bv,
                           float* __restrict__ xn, float* __restrict__ Qb,
                           float* __restrict__ Kx, float* __restrict__ Vx,
                           const float* __restrict__ w1, const float* __restrict__ w2,
                           const float* __restrict__ WOe,
                           const float* __restrict__ Wqn, const float* __restrict__ Wke,
                           const float* __restrict__ Wve,
                           unsigned short* __restrict__ w1f, unsigned short* __restrict__ w2f,
                           unsigned short* __restrict__ WOef,
                           unsigned short* __restrict__ Wqf, unsigned short* __restrict__ Wkf,
                           unsigned short* __restrict__ Wvf) {
    int t = threadIdx.x;
    if (blockIdx.x < 48) {
        __shared__ float xs[8][DD];
        __shared__ float mred[8], rred[8];
        int r0 = blockIdx.x * 8;
        for (int r = 0; r < 8; r++) xs[r][t] = x[(r0 + r) * DD + t];
        __syncthreads();
        ln8(xs, lnxg, lnxb, mred, rred);
        for (int r = 0; r < 8; r++) xn[(r0 + r) * DD + t] = xs[r][t];
        int h = t >> 5, d_ = t & 31;
        const float* wq = Wq + h * DD * DHH + d_;
        const float* wk = Wk + h * DD * DHH + d_;
        const float* wv = Wv + h * DD * DHH + d_;
        float aq[8] = {0}, ak[8] = {0}, av[8] = {0};
        for (int k = 0; k < DD; k++) {
            float w1v = wq[k * DHH], w2v = wk[k * DHH], w3v = wv[k * DHH];
#pragma unroll
            for (int r = 0; r < 8; r++) {
                float ev = xs[r][k];
                aq[r] += ev * w1v; ak[r] += ev * w2v; av[r] += ev * w3v;
            }
        }
        float bqt = bq[t], bkt = bk[t], bvt = bv[t];
        for (int r = 0; r < 8; r++) {
            Qb[(r0 + r) * DD + t] = aq[r] + bqt;
            Kx[(r0 + r) * DD + t] = ak[r] + bkt;
            Vx[(r0 + r) * DD + t] = av[r] + bvt;
        }
        return;
    }
    int bid = blockIdx.x - 48;
    short8 out;
    if (bid < 128) {
        int fi = bid * 256 + t;            // fragment index, 32768 total
        int l = fi & 63, g = fi >> 6;      // g = tau*8 + kap, tau<64
        int fr = l & 15, fq = l >> 4;
        int tau = g >> 3, kap = g & 7;
        const float* src = w1 + (size_t)(tau * 16 + fr) * 256 + kap * 32 + fq * 8;
#pragma unroll
        for (int u = 0; u < 8; u++) out[u] = (short)f2bf(src[u]);
        *(short8*)(w1f + (size_t)fi * 8) = out;
    } else if (bid < 256) {
        int fi = (bid - 128) * 256 + t;
        int l = fi & 63, g = fi >> 6;      // g = tau2*32 + kap2, tau2<16
        int fr = l & 15, fq = l >> 4;
        int tau = g >> 5, kap = g & 31;
        const float* src = w2 + (size_t)(tau * 16 + fr) * 1024 + kap * 32 + fq * 8;
#pragma unroll
        for (int u = 0; u < 8; u++) out[u] = (short)f2bf(src[u]);
        *(short8*)(w2f + (size_t)fi * 8) = out;
    } else if (bid < 288) {
        int fi = (bid - 256) * 256 + t;    // 8192 frags
        int l = fi & 63, g = fi >> 6;
        int fr = l & 15, fq = l >> 4;
        int tau = g >> 3, kap = g & 7;
        const float* src = WOe + (size_t)(tau * 16 + fr) * 256 + kap * 32 + fq * 8;
#pragma unroll
        for (int u = 0; u < 8; u++) out[u] = (short)f2bf(src[u]);
        *(short8*)(WOef + (size_t)fi * 8) = out;
    } else {
        int which = (bid - 288) >> 5;      // 0=Wq 1=Wk 2=Wv
        int fi = ((bid - 288) & 31) * 256 + t;
        int l = fi & 63, g = fi >> 6;
        int fr = l & 15, fq = l >> 4;
        int tau = g >> 3, kap = g & 7;
        int n = tau * 16 + fr;
        int k0 = kap * 32 + fq * 8;
        const float* src = which == 0 ? Wqn : which == 1 ? Wke : Wve;
        const float* s2 = src + (size_t)(n >> 5) * 8192 + (n & 31);
#pragma unroll
        for (int u = 0; u < 8; u++) out[u] = (short)f2bf(s2[(size_t)(k0 + u) * 32]);
        unsigned short* dst = which == 0 ? Wqf : which == 1 ? Wkf : Wvf;
        *(short8*)(dst + (size_t)fi * 8) = out;
    }
}

// ---------- kernel 2 (FUSED, M=64): n2e attn + WOe + resid + LN2 + e-MLP
//            + e2n attention PARTIAL. grid 1152, block 512 = 8 waves. ----------
__global__ __launch_bounds__(512, 2) void k_n2e_fused(
    const float* __restrict__ e,
    const float* __restrict__ lneg, const float* __restrict__ lneb,
    const unsigned short* __restrict__ Wqf, const float* __restrict__ bq,
    const unsigned short* __restrict__ Wkf, const float* __restrict__ bk,
    const unsigned short* __restrict__ Wvf, const float* __restrict__ bv,
    const float* __restrict__ Kx, const float* __restrict__ Vx,
    const float* __restrict__ Qb,
    const unsigned short* __restrict__ WOef, const float* __restrict__ WOb,
    const float* __restrict__ ln2g, const float* __restrict__ ln2b,
    const unsigned short* __restrict__ w1f, const float* __restrict__ b1,
    const unsigned short* __restrict__ w2f, const float* __restrict__ b2,
    float* __restrict__ oute,
    float* __restrict__ accP3, float* __restrict__ mP3, float* __restrict__ lP3) {
    __shared__ unsigned short a_bf[64][264];   // LN(e) tile -> later h tile
    __shared__ unsigned short p_bf[64][264];   // e_heads -> later LN2 A-tile
    __shared__ float KxiS[DD], VxiS[DD], QbS[DD];
    __shared__ float mrow[64], rrow[64];
    __shared__ float sW[64][8], s2W[64][8];
    __shared__ float m2s[64], r2s[64];
    int t = threadIdx.x, lane = t & 63, w = t >> 6;   // 8 waves
    int fr = lane & 15, fq = lane >> 4;
    int blk = blockIdx.x;
    int b   = blk / (NN * 3);
    int rem = blk % (NN * 3);
    int i   = rem / 3;
    int spl = rem % 3;
    int j0  = spl * 64;
    int node = b * NN + i;
    size_t ebase = ((size_t)node * NN + j0) * DD;

    // ---- LN of 64 rows -> a_bf (bf16); keep mean/rstd. 8 thr/row, 32 cols each.
    {
        int r = t >> 3, sub = t & 7;
        const float4* src4 = (const float4*)(e + ebase + (size_t)r * DD + sub * 32);
        float vals[32];
        float s = 0.f, s2 = 0.f;
#pragma unroll
        for (int u = 0; u < 8; u++) {
            float4 v = src4[u];
            vals[4 * u + 0] = v.x; vals[4 * u + 1] = v.y;
            vals[4 * u + 2] = v.z; vals[4 * u + 3] = v.w;
            s += v.x + v.y + v.z + v.w;
            s2 += v.x * v.x + v.y * v.y + v.z * v.z + v.w * v.w;
        }
        s += __shfl_xor(s, 4); s2 += __shfl_xor(s2, 4);
        s += __shfl_xor(s, 2); s2 += __shfl_xor(s2, 2);
        s += __shfl_xor(s, 1); s2 += __shfl_xor(s2, 1);
        float mean = s * (1.f / 256.f);
        float rstd = rsqrtf(s2 * (1.f / 256.f) - mean * mean + 1e-5f);
        if (sub == 0) { mrow[r] = mean; rrow[r] = rstd; }
#pragma unroll
        for (int u = 0; u < 32; u += 2) {
            int col = sub * 32 + u;
            float n0 = (vals[u]     - mean) * rstd * lneg[col]     + lneb[col];
            float n1 = (vals[u + 1] - mean) * rstd * lneg[col + 1] + lneb[col + 1];
            unsigned int pk = (unsigned int)f2bf(n0) | ((unsigned int)f2bf(n1) << 16);
            *(unsigned int*)&a_bf[r][col] = pk;
        }
    }
    if (t < DD) {
        KxiS[t] = Kx[node * DD + t];
        VxiS[t] = Vx[node * DD + t];
        QbS[t]  = Qb[node * DD + t];
    }
    __syncthreads();

    const int nw = w * 32;   // this wave's 32-col slice = head w

    // ---- GEMM: K_en (keep in regs, bias included)
    f32x4 accK[4][2];
    gemm256m4(a_bf, Wkf, w, lane, fr, fq, accK);
#pragma unroll
    for (int nt = 0; nt < 2; nt++) {
        float bb = bk[nw + nt * 16 + fr];
#pragma unroll
        for (int m = 0; m < 4; m++)
#pragma unroll
            for (int j = 0; j < 4; j++) accK[m][nt][j] += bb;
    }

    // ---- GEMM: V_en (keep in regs, bias included)
    f32x4 accV[4][2];
    gemm256m4(a_bf, Wvf, w, lane, fr, fq, accV);
#pragma unroll
    for (int nt = 0; nt < 2; nt++) {
        float bb = bv[nw + nt * 16 + fr];
#pragma unroll
        for (int m = 0; m < 4; m++)
#pragma unroll
            for (int j = 0; j < 4; j++) accV[m][nt][j] += bb;
    }

    // ---- e2n attention PARTIAL over this block's 64 j-rows (split spl)
    {
        float QbL[2];
        QbL[0] = QbS[nw + fr];
        QbL[1] = QbS[nw + 16 + fr];
        float p[4][4];
        float mx = -1e30f;
#pragma unroll
        for (int m = 0; m < 4; m++)
#pragma unroll
            for (int j = 0; j < 4; j++) {
                float s = accK[m][0][j] * QbL[0] + accK[m][1][j] * QbL[1];
                s += __shfl_xor(s, 1);
                s += __shfl_xor(s, 2);
                s += __shfl_xor(s, 4);
                s += __shfl_xor(s, 8);
                s *= SCALE;
                p[m][j] = s;
                mx = fmaxf(mx, s);
            }
        mx = fmaxf(mx, __shfl_xor(mx, 16));
        mx = fmaxf(mx, __shfl_xor(mx, 32));
        float lsum = 0.f;
#pragma unroll
        for (int m = 0; m < 4; m++)
#pragma unroll
            for (int j = 0; j < 4; j++) {
                p[m][j] = __expf(p[m][j] - mx);
                lsum += p[m][j];
            }
        lsum += __shfl_xor(lsum, 16);
        lsum += __shfl_xor(lsum, 32);
        float part[2];
#pragma unroll
        for (int nt = 0; nt < 2; nt++) {
            float acc = 0.f;
#pragma unroll
            for (int m = 0; m < 4; m++)
#pragma unroll
                for (int j = 0; j < 4; j++)
                    acc += p[m][j] * accV[m][nt][j];
            acc += __shfl_xor(acc, 16);
            acc += __shfl_xor(acc, 32);
            part[nt] = acc;
        }
        if (fq == 0) {
#pragma unroll
            for (int nt = 0; nt < 2; nt++)
                accP3[((size_t)spl * BB * NN + node) * DD + nw + nt * 16 + fr] = part[nt];
            if (fr == 0) {
                mP3[((size_t)spl * BB * NN + node) * HH + w] = mx;
                lP3[((size_t)spl * BB * NN + node) * HH + w] = lsum;
            }
        }
    }

    // ---- GEMM: Qe
    f32x4 accQ[4][2];
    gemm256m4(a_bf, Wqf, w, lane, fr, fq, accQ);
    {
        float bqv[2];
#pragma unroll
        for (int nt = 0; nt < 2; nt++) bqv[nt] = bq[nw + nt * 16 + fr];
#pragma unroll
        for (int m = 0; m < 4; m++)
#pragma unroll
            for (int nt = 0; nt < 2; nt++)
#pragma unroll
                for (int j = 0; j < 4; j++) accQ[m][nt][j] += bqv[nt];
    }

    // ---- n2e scores: si = Qe . Kx[i], sj = Qe . Kx[j]; softmax over {i,j}
    float KxiL[2], VxiL[2];
#pragma unroll
    for (int nt = 0; nt < 2; nt++) {
        KxiL[nt] = KxiS[nw + nt * 16 + fr];
        VxiL[nt] = VxiS[nw + nt * 16 + fr];
    }
    float ai[4][4], aj[4][4];   // [m][j] (one head per wave)
#pragma unroll
    for (int m = 0; m < 4; m++)
#pragma unroll
        for (int j = 0; j < 4; j++) {
            int row = m * 16 + fq * 4 + j;
            float k0v = Kx[(size_t)(b * NN + j0 + row) * DD + nw + fr];
            float k1v = Kx[(size_t)(b * NN + j0 + row) * DD + nw + 16 + fr];
            float p = accQ[m][0][j] * KxiL[0] + accQ[m][1][j] * KxiL[1];
            float q = accQ[m][0][j] * k0v + accQ[m][1][j] * k1v;
#pragma unroll
            for (int mk = 1; mk <= 8; mk <<= 1) {
                p += __shfl_xor(p, mk);
                q += __shfl_xor(q, mk);
            }
            p *= SCALE; q *= SCALE;
            float mx = fmaxf(p, q);
            float ei = __expf(p - mx), ej = __expf(q - mx);
            float inv = 1.f / (ei + ej);
            ai[m][j] = ei * inv; aj[m][j] = ej * inv;
        }
    // ---- e_heads = ai*Vx[i] + aj*Vx[j] -> p_bf
#pragma unroll
    for (int m = 0; m < 4; m++)
#pragma unroll
        for (int j = 0; j < 4; j++) {
            int row = m * 16 + fq * 4 + j;
            float v0 = Vx[(size_t)(b * NN + j0 + row) * DD + nw + fr];
            float v1 = Vx[(size_t)(b * NN + j0 + row) * DD + nw + 16 + fr];
            p_bf[row][nw + fr]      = f2bf(ai[m][j] * VxiL[0] + aj[m][j] * v0);
            p_bf[row][nw + 16 + fr] = f2bf(ai[m][j] * VxiL[1] + aj[m][j] * v1);
        }
    __syncthreads();

    // ---- GEMM: e_heads @ WOe^T
    f32x4 accO[4][2];
    gemm256m4(p_bf, WOef, w, lane, fr, fq, accO);

    // ---- epre = fp32 LN1 residual + accO + bo  (kept in registers)
    float epre[4][2][4];
#pragma unroll
    for (int nt = 0; nt < 2; nt++) {
        int col = nw + nt * 16 + fr;
        float bo = WOb[col];
        float gc = lneg[col], bc = lneb[col];
#pragma unroll
        for (int m = 0; m < 4; m++)
#pragma unroll
            for (int j = 0; j < 4; j++) {
                int row = m * 16 + fq * 4 + j;
                float ev = e[ebase + (size_t)row * DD + col];
                float resid = (ev - mrow[row]) * rrow[row] * gc + bc;
                epre[m][nt][j] = resid + accO[m][nt][j] + bo;
            }
    }

    // ---- LN2 stats (cross-lane over fr, cross-wave via LDS)
#pragma unroll
    for (int m = 0; m < 4; m++)
#pragma unroll
        for (int j = 0; j < 4; j++) {
            float s  = epre[m][0][j] + epre[m][1][j];
            float s2 = epre[m][0][j] * epre[m][0][j] + epre[m][1][j] * epre[m][1][j];
#pragma unroll
            for (int mk = 1; mk <= 8; mk <<= 1) {
                s += __shfl_xor(s, mk);
                s2 += __shfl_xor(s2, mk);
            }
            if (fr == 0) {
                int row = m * 16 + fq * 4 + j;
                sW[row][w] = s;
                s2W[row][w] = s2;
            }
        }
    __syncthreads();   // all reads of p_bf (WOe GEMM) done -> safe to overwrite
    if (t < 64) {
        float S = 0.f, S2 = 0.f;
#pragma unroll
        for (int ww = 0; ww < 8; ww++) { S += sW[t][ww]; S2 += s2W[t][ww]; }
        float mean = S * (1.f / 256.f);
        float var  = S2 * (1.f / 256.f) - mean * mean;
        m2s[t] = mean;
        r2s[t] = rsqrtf(var + 1e-5f);
    }
    __syncthreads();

    // ---- LN2(epre) bf16 -> p_bf (MLP A-tile)
#pragma unroll
    for (int nt = 0; nt < 2; nt++) {
        int col = nw + nt * 16 + fr;
        float g2 = ln2g[col], b2c = ln2b[col];
#pragma unroll
        for (int m = 0; m < 4; m++)
#pragma unroll
            for (int j = 0; j < 4; j++) {
                int row = m * 16 + fq * 4 + j;
                p_bf[row][col] = f2bf((epre[m][nt][j] - m2s[row]) * r2s[row] * g2 + b2c);
            }
    }
    __syncthreads();

    // ---- e-MLP: A = p_bf, h -> a_bf (reuse), accumulate accM
#define B1ADDR(c, nt, k) (w1f + (((size_t)((c) * 16 + w * 2 + (nt)) * 8 + (k)) * 64 + lane) * 8)
#define B2ADDR(nt, c, k) (w2f + (((size_t)(w * 2 + (nt)) * 32 + (c) * 8 + (k)) * 64 + lane) * 8)
    f32x4 accM[4][2];
#pragma unroll
    for (int m = 0; m < 4; m++)
#pragma unroll
        for (int nt = 0; nt < 2; nt++) accM[m][nt] = (f32x4){0.f, 0.f, 0.f, 0.f};

    for (int c = 0; c < 4; c++) {
        f32x4 acc1[4][2];
#pragma unroll
        for (int m = 0; m < 4; m++)
#pragma unroll
            for (int nt = 0; nt < 2; nt++) acc1[m][nt] = (f32x4){0.f, 0.f, 0.f, 0.f};
        {
            short8 nb[2];
#pragma unroll
            for (int nt = 0; nt < 2; nt++) nb[nt] = *(const short8*)B1ADDR(c, nt, 0);
            __builtin_amdgcn_s_setprio(1);
#pragma unroll
            for (int k = 0; k < 8; k++) {
                short8 cb[2];
#pragma unroll
                for (int nt = 0; nt < 2; nt++) cb[nt] = nb[nt];
                if (k < 7) {
#pragma unroll
                    for (int nt = 0; nt < 2; nt++) nb[nt] = *(const short8*)B1ADDR(c, nt, k + 1);
                }
                short8 av[4];
#pragma unroll
                for (int m = 0; m < 4; m++)
                    av[m] = *(const short8*)&p_bf[m * 16 + fr][k * 32 + fq * 8];
#pragma unroll
                for (int nt = 0; nt < 2; nt++)
#pragma unroll
                    for (int m = 0; m < 4; m++)
                        acc1[m][nt] = __builtin_amdgcn_mfma_f32_16x16x32_bf16(av[m], cb[nt], acc1[m][nt], 0, 0, 0);
            }
            __builtin_amdgcn_s_setprio(0);
        }
#pragma unroll
        for (int nt = 0; nt < 2; nt++) {
            int ncol = nw + nt * 16 + fr;
            float bias = b1[c * 256 + ncol];
#pragma unroll
            for (int m = 0; m < 4; m++)
#pragma unroll
                for (int j = 0; j < 4; j++) {
                    float v = acc1[m][nt][j] + bias;
                    v = v > 0.f ? v : 0.01f * v;
                    a_bf[m * 16 + fq * 4 + j][ncol] = f2bf(v);
                }
        }
        __syncthreads();
        {
            short8 nb[2];
#pragma unroll
            for (int nt = 0; nt < 2; nt++) nb[nt] = *(const short8*)B2ADDR(nt, c, 0);
            __builtin_amdgcn_s_setprio(1);
#pragma unroll
            for (int k = 0; k < 8; k++) {
                short8 cb[2];
#pragma unroll
                for (int nt = 0; nt < 2; nt++) cb[nt] = nb[nt];
                if (k < 7) {
#pragma unroll
                    for (int nt = 0; nt < 2; nt++) nb[nt] = *(const short8*)B2ADDR(nt, c, k + 1);
                }
                short8 hv[4];
#pragma unroll
                for (int m = 0; m < 4; m++)
                    hv[m] = *(const short8*)&a_bf[m * 16 + fr][k * 32 + fq * 8];
#pragma unroll
                for (int nt = 0; nt < 2; nt++)
#pragma unroll
                    for (int m = 0; m < 4; m++)
                        accM[m][nt] = __builtin_amdgcn_mfma_f32_16x16x32_bf16(hv[m], cb[nt], accM[m][nt], 0, 0, 0);
            }
            __builtin_amdgcn_s_setprio(0);
        }
        __syncthreads();   // protect a_bf before next chunk's h writes
    }
#undef B1ADDR
#undef B2ADDR

    // ---- final: e_out = epre + mlp + b2
#pragma unroll
    for (int nt = 0; nt < 2; nt++) {
        int col = nw + nt * 16 + fr;
        float bias = b2[col];
#pragma unroll
        for (int m = 0; m < 4; m++)
#pragma unroll
            for (int j = 0; j < 4; j++) {
                int row = m * 16 + fq * 4 + j;
                oute[ebase + (size_t)row * DD + col] = epre[m][nt][j] + accM[m][nt][j] + bias;
            }
    }
}

// ---------- merge kernel, parameterized split count (fallback path) ----------
__global__ void k_e2n_mergeN(const float* __restrict__ accP, const float* __restrict__ mP,
                             const float* __restrict__ lP, float* __restrict__ xh,
                             int nsplit) {
    int t = threadIdx.x, row = blockIdx.x, h = t >> 5;
    float m = -1e30f;
    for (int s = 0; s < nsplit; s++) m = fmaxf(m, mP[(s * BB * NN + row) * HH + h]);
    float num = 0.f, den = 0.f;
    for (int s = 0; s < nsplit; s++) {
        float c = __expf(mP[(s * BB * NN + row) * HH + h] - m);
        num += accP[((size_t)s * BB * NN + row) * DD + t] * c;
        den += lP[(s * BB * NN + row) * HH + h] * c;
    }
    xh[row * DD + t] = num / den;
}

// ---------- kernel 4 (MERGED, 4 rows/block): 3-split e2n merge + WOx + resid + LN2 + MLP ----------
// grid 96 (BB*NN/4) for better CU coverage; one wave per row in LN stats.
__global__ void k_x_epi3(const float* __restrict__ accP3, const float* __restrict__ mP3,
                         const float* __restrict__ lP3,
                         const float* __restrict__ xn,
                         const float* __restrict__ WO, const float* __restrict__ WOb,
                         const float* __restrict__ ln2g, const float* __restrict__ ln2b,
                         const float* __restrict__ w1, const float* __restrict__ b1,
                         const float* __restrict__ w2, const float* __restrict__ b2,
                         float* __restrict__ outx) {
    __shared__ float hsrc[4][DD];
    __shared__ float xs[4][DD];
    __shared__ float ls[4][DD];
    __shared__ float hh[4][1024];
    __shared__ float mred[4], rred[4];
    int t = threadIdx.x;
    int r0 = blockIdx.x * 4;
    int h = t >> 5;
    // inline 3-split merge -> hsrc
    for (int r = 0; r < 4; r++) {
        int row = r0 + r;
        float m = -1e30f;
#pragma unroll
        for (int s = 0; s < NS3; s++) m = fmaxf(m, mP3[(s * BB * NN + row) * HH + h]);
        float num = 0.f, den = 0.f;
#pragma unroll
        for (int s = 0; s < NS3; s++) {
            float c = __expf(mP3[(s * BB * NN + row) * HH + h] - m);
            num += accP3[((size_t)s * BB * NN + row) * DD + t] * c;
            den += lP3[(s * BB * NN + row) * HH + h] * c;
        }
        hsrc[r][t] = num / den;
    }
    __syncthreads();
    float acc[4] = {0};
    const float* wrow = WO + (size_t)t * DD;
    for (int k = 0; k < DD; k++) {
        float w = wrow[k];
#pragma unroll
        for (int r = 0; r < 4; r++) acc[r] += hsrc[r][k] * w;
    }
    float wob = WOb[t];
    for (int r = 0; r < 4; r++) {
        float v = xn[(r0 + r) * DD + t] + acc[r] + wob;
        xs[r][t] = v;
        ls[r][t] = v;
    }
    __syncthreads();
    // LN: one wave per row (r = t>>6, l = t&63, each lane sums 4 cols)
    {
        int r = t >> 6, l = t & 63;
        float s = 0.f, s2 = 0.f;
#pragma unroll
        for (int u = 0; u < 4; u++) {
            float v = ls[r][l + 64 * u];
            s += v; s2 += v * v;
        }
        s = red64(s); s2 = red64(s2);
        if (l == 0) {
            float mean = s * (1.f / 256.f);
            float var  = s2 * (1.f / 256.f) - mean * mean;
            mred[r] = mean;
            rred[r] = rsqrtf(var + 1e-5f);
        }
    }
    __syncthreads();
    {
        float gt = ln2g[t], bt = ln2b[t];
#pragma unroll
        for (int rr = 0; rr < 4; rr++) {
            float v = ls[rr][t];
            ls[rr][t] = (v - mred[rr]) * rred[rr] * gt + bt;
        }
    }
    __syncthreads();
    for (int p = 0; p < 4; p++) {
        int q = t + p * 256;
        float a2[4] = {0};
        const float* w1r = w1 + (size_t)q * DD;
        for (int k = 0; k < DD; k++) {
            float w = w1r[k];
#pragma unroll
            for (int r = 0; r < 4; r++) a2[r] += ls[r][k] * w;
        }
        float b1q = b1[q];
        for (int r = 0; r < 4; r++) {
            float v = a2[r] + b1q;
            hh[r][q] = v > 0.f ? v : 0.01f * v;
        }
    }
    __syncthreads();
    float a3[4] = {0};
    const float* w2r = w2 + (size_t)t * 1024;
    for (int q = 0; q < 1024; q++) {
        float w = w2r[q];
#pragma unroll
        for (int r = 0; r < 4; r++) a3[r] += hh[r][q] * w;
    }
    float b2t = b2[t];
    for (int r = 0; r < 4; r++)
        outx[(r0 + r) * DD + t] = xs[r][t] + a3[r] + b2t;
}

// ---------- kernel 4 (fallback): x epilogue reading xh ----------
__global__ void k_x_epi(const float* __restrict__ xh, const float* __restrict__ xn,
                        const float* __restrict__ WO, const float* __restrict__ WOb,
                        const float* __restrict__ ln2g, const float* __restrict__ ln2b,
                        const float* __restrict__ w1, const float* __restrict__ b1,
                        const float* __restrict__ w2, const float* __restrict__ b2,
                        float* __restrict__ outx) {
    __shared__ float hsrc[8][DD];
    __shared__ float xs[8][DD];
    __shared__ float ls[8][DD];
    __shared__ float hh[8][1024];
    __shared__ float mred[8], rred[8];
    int t = threadIdx.x;
    int r0 = blockIdx.x * 8;
    for (int r = 0; r < 8; r++) hsrc[r][t] = xh[(r0 + r) * DD + t];
    __syncthreads();
    float acc[8] = {0};
    const float* wrow = WO + (size_t)t * DD;
    for (int k = 0; k < DD; k++) {
        float w = wrow[k];
#pragma unroll
        for (int r = 0; r < 8; r++) acc[r] += hsrc[r][k] * w;
    }
    float wob = WOb[t];
    for (int r = 0; r < 8; r++) {
        float v = xn[(r0 + r) * DD + t] + acc[r] + wob;
        xs[r][t] = v;
        ls[r][t] = v;
    }
    __syncthreads();
    ln8(ls, ln2g, ln2b, mred, rred);
    for (int p = 0; p < 4; p++) {
        int q = t + p * 256;
        float a2[8] = {0};
        const float* w1r = w1 + (size_t)q * DD;
        for (int k = 0; k < DD; k++) {
            float w = w1r[k];
#pragma unroll
            for (int r = 0; r < 8; r++) a2[r] += ls[r][k] * w;
        }
        float b1q = b1[q];
        for (int r = 0; r < 8; r++) {
            float v = a2[r] + b1q;
            hh[r][q] = v > 0.f ? v : 0.01f * v;
        }
    }
    __syncthreads();
    float a3[8] = {0};
    const float* w2r = w2 + (size_t)t * 1024;
    for (int q = 0; q < 1024; q++) {
        float w = w2r[q];
#pragma unroll
        for (int r = 0; r < 8; r++) a3[r] += hh[r][q] * w;
    }
    float b2t = b2[t];
    for (int r = 0; r < 8; r++)
        outx[(r0 + r) * DD + t] = xs[r][t] + a3[r] + b2t;
}

// ---------- FALLBACK kernels (fp32, used only if ws too small) ----------
__global__ void k_node_prep(const float* __restrict__ x,
                            const float* __restrict__ lnxg, const float* __restrict__ lnxb,
                            const float* __restrict__ Wq, const float* __restrict__ bq,
                            const float* __restrict__ Wk, const float* __restrict__ bk,
                            const float* __restrict__ Wv, const float* __restrict__ bv,
                            float* __restrict__ xn, float* __restrict__ Qb,
                            float* __restrict__ Kx, float* __restrict__ Vx) {
    __shared__ float xs[8][DD];
    __shared__ float mred[8], rred[8];
    int t = threadIdx.x;
    int r0 = blockIdx.x * 8;
    for (int r = 0; r < 8; r++) xs[r][t] = x[(r0 + r) * DD + t];
    __syncthreads();
    ln8(xs, lnxg, lnxb, mred, rred);
    for (int r = 0; r < 8; r++) xn[(r0 + r) * DD + t] = xs[r][t];
    int h = t >> 5, d_ = t & 31;
    const float* wq = Wq + h * DD * DHH + d_;
    const float* wk = Wk + h * DD * DHH + d_;
    const float* wv = Wv + h * DD * DHH + d_;
    float aq[8] = {0}, ak[8] = {0}, av[8] = {0};
    for (int k = 0; k < DD; k++) {
        float w1 = wq[k * DHH], w2 = wk[k * DHH], w3 = wv[k * DHH];
#pragma unroll
        for (int r = 0; r < 8; r++) {
            float e = xs[r][k];
            aq[r] += e * w1; ak[r] += e * w2; av[r] += e * w3;
        }
    }
    float bqt = bq[t], bkt = bk[t], bvt = bv[t];
    for (int r = 0; r < 8; r++) {
        Qb[(r0 + r) * DD + t] = aq[r] + bqt;
        Kx[(r0 + r) * DD + t] = ak[r] + bkt;
        Vx[(r0 + r) * DD + t] = av[r] + bvt;
    }
}

__global__ void k_e2n_attn(const float* __restrict__ e,
                           const float* __restrict__ lneg, const float* __restrict__ lneb,
                           const float* __restrict__ Wk, const float* __restrict__ bk,
                           const float* __restrict__ Wv, const float* __restrict__ bv,
                           const float* __restrict__ Qb,
                           float* __restrict__ accP, float* __restrict__ mP,
                           float* __restrict__ lP) {
    __shared__ float es[8][DD];
    __shared__ float mred[8], rred[8];
    int t = threadIdx.x;
    int s = blockIdx.x & (SJ - 1);
    int row = blockIdx.x >> 2;
    int h = t >> 5, d_ = t & 31;
    float qt = Qb[row * DD + t];
    float m_s = -1e30f, l_s = 0.f, acc = 0.f;
    const float* wk = Wk + h * DD * DHH + d_;
    const float* wv = Wv + h * DD * DHH + d_;
    float bkt = bk[t], bvt = bv[t];
    for (int j0 = s * (NN / SJ); j0 < (s + 1) * (NN / SJ); j0 += 8) {
        for (int r = 0; r < 8; r++)
            es[r][t] = e[((size_t)row * NN + j0 + r) * DD + t];
        __syncthreads();
        ln8(es, lneg, lneb, mred, rred);
        float aK[8] = {0}, aV[8] = {0};
        for (int k = 0; k < DD; k++) {
            float w1 = wk[k * DHH], w2 = wv[k * DHH];
#pragma unroll
            for (int r = 0; r < 8; r++) {
                float ev = es[r][k];
                aK[r] += ev * w1; aV[r] += ev * w2;
            }
        }
#pragma unroll
        for (int r = 0; r < 8; r++) {
            float sc = red32(qt * (aK[r] + bkt)) * SCALE;
            float vn = aV[r] + bvt;
            float mn = fmaxf(m_s, sc);
            float c = __expf(m_s - mn);
            float p = __expf(sc - mn);
            l_s = l_s * c + p;
            acc = acc * c + p * vn;
            m_s = mn;
        }
        __syncthreads();
    }
    accP[((size_t)s * BB * NN + row) * DD + t] = acc;
    if (d_ == 0) {
        mP[(s * BB * NN + row) * HH + h] = m_s;
        lP[(s * BB * NN + row) * HH + h] = l_s;
    }
}

__global__ void k_n2e(const float* __restrict__ e,
                      const float* __restrict__ lneg, const float* __restrict__ lneb,
                      const float* __restrict__ Wq, const float* __restrict__ bq,
                      const float* __restrict__ Kx, const float* __restrict__ Vx,
                      const float* __restrict__ WO, const float* __restrict__ WOb,
                      float* __restrict__ oute) {
    __shared__ float es[8][DD];
    __shared__ float hs[8][DD];
    __shared__ float mred[8], rred[8];
    int t = threadIdx.x, h = t >> 5, d_ = t & 31;
    int blk = blockIdx.x;
    int b = blk / (NN * (NN / 8));
    int rem = blk % (NN * (NN / 8));
    int i = rem / (NN / 8);
    int j0 = (rem % (NN / 8)) * 8;
    size_t ebase = ((size_t)(b * NN + i) * NN + j0) * DD;
    for (int r = 0; r < 8; r++) es[r][t] = e[ebase + (size_t)r * DD + t];
    __syncthreads();
    ln8(es, lneg, lneb, mred, rred);
    float aQ[8] = {0};
    const float* wq = Wq + h * DD * DHH + d_;
    for (int k = 0; k < DD; k++) {
        float w = wq[k * DHH];
#pragma unroll
        for (int r = 0; r < 8; r++) aQ[r] += es[r][k] * w;
    }
    float bqt = bq[t];
    float kxi = Kx[(b * NN + i) * DD + t];
    float vxi = Vx[(b * NN + i) * DD + t];
#pragma unroll
    for (int r = 0; r < 8; r++) {
        float qe = aQ[r] + bqt;
        float si = red32(qe * kxi) * SCALE;
        float kxj = Kx[(b * NN + j0 + r) * DD + t];
        float sj = red32(qe * kxj) * SCALE;
        float mx = fmaxf(si, sj);
        float ei = __expf(si - mx), ej = __expf(sj - mx);
        float inv = 1.f / (ei + ej);
        float vxj = Vx[(b * NN + j0 + r) * DD + t];
        hs[r][t] = (ei * inv) * vxi + (ej * inv) * vxj;
    }
    __syncthreads();
    float aO[8] = {0};
    const float* wrow = WO + (size_t)t * DD;
    for (int k = 0; k < DD; k++) {
        float w = wrow[k];
#pragma unroll
        for (int r = 0; r < 8; r++) aO[r] += hs[r][k] * w;
    }
    float wob = WOb[t];
    for (int r = 0; r < 8; r++)
        oute[ebase + (size_t)r * DD + t] = es[r][t] + aO[r] + wob;
}

// ---------- fp32 e-MLP fallback ----------
__global__ void k_e_mlp_f32(float* __restrict__ oute,
                            const float* __restrict__ ln2g, const float* __restrict__ ln2b,
                            const float* __restrict__ w1, const float* __restrict__ b1,
                            const float* __restrict__ w2, const float* __restrict__ b2) {
    __shared__ float xs[8][DD];
    __shared__ float ls[8][DD];
    __shared__ float hh[8][1024];
    __shared__ float mred[8], rred[8];
    int t = threadIdx.x;
    size_t r0 = (size_t)blockIdx.x * 8;
    for (int r = 0; r < 8; r++) {
        float v = oute[(r0 + r) * DD + t];
        xs[r][t] = v;
        ls[r][t] = v;
    }
    __syncthreads();
    ln8(ls, ln2g, ln2b, mred, rred);
    for (int p = 0; p < 4; p++) {
        int q = t + p * 256;
        float a2[8] = {0};
        const float* w1r = w1 + (size_t)q * DD;
        for (int k = 0; k < DD; k++) {
            float w = w1r[k];
#pragma unroll
            for (int r = 0; r < 8; r++) a2[r] += ls[r][k] * w;
        }
        float b1q = b1[q];
        for (int r = 0; r < 8; r++) {
            float v = a2[r] + b1q;
            hh[r][q] = v > 0.f ? v : 0.01f * v;
        }
    }
    __syncthreads();
    float a3[8] = {0};
    const float* w2r = w2 + (size_t)t * 1024;
    for (int q = 0; q < 1024; q++) {
        float w = w2r[q];
#pragma unroll
        for (int r = 0; r < 8; r++) a3[r] += hh[r][q] * w;
    }
    float b2t = b2[t];
    for (int r = 0; r < 8; r++)
        oute[(r0 + r) * DD + t] = xs[r][t] + a3[r] + b2t;
}

// ---------- launch ----------
extern "C" void kernel_launch(void* const* d_in, const int* in_sizes, int n_in,
                              void* d_out, int out_size, void* d_ws, size_t ws_size,
                              hipStream_t stream) {
    (void)in_sizes; (void)n_in; (void)out_size;
    const float* x      = (const float*)d_in[0];
    const float* e      = (const float*)d_in[1];
    const float* ln_x_g = (const float*)d_in[2];
    const float* ln_x_b = (const float*)d_in[3];
    const float* ln_e_g = (const float*)d_in[4];
    const float* ln_e_b = (const float*)d_in[5];
    const float* ln_x2_g = (const float*)d_in[6];
    const float* ln_x2_b = (const float*)d_in[7];
    const float* ln_e2_g = (const float*)d_in[8];
    const float* ln_e2_b = (const float*)d_in[9];
    const float* Wq_en = (const float*)d_in[10];
    const float* bq_en = (const float*)d_in[11];
    const float* Wk_en = (const float*)d_in[12];
    const float* bk_en = (const float*)d_in[13];
    const float* Wv_en = (const float*)d_in[14];
    const float* bv_en = (const float*)d_in[15];
    const float* Wq_ne = (const float*)d_in[16];
    const float* bq_ne = (const float*)d_in[17];
    const float* Wk_ne = (const float*)d_in[18];
    const float* bk_ne = (const float*)d_in[19];
    const float* Wv_ne = (const float*)d_in[20];
    const float* bv_ne = (const float*)d_in[21];
    const float* WOx_w = (const float*)d_in[22];
    const float* WOx_b = (const float*)d_in[23];
    const float* WOe_w = (const float*)d_in[24];
    const float* WOe_b = (const float*)d_in[25];
    const float* mlpx_w1 = (const float*)d_in[26];
    const float* mlpx_b1 = (const float*)d_in[27];
    const float* mlpx_w2 = (const float*)d_in[28];
    const float* mlpx_b2 = (const float*)d_in[29];
    const float* mlpe_w1 = (const float*)d_in[30];
    const float* mlpe_b1 = (const float*)d_in[31];
    const float* mlpe_w2 = (const float*)d_in[32];
    const float* mlpe_b2 = (const float*)d_in[33];

    float* out_x = (float*)d_out;
    float* out_e = out_x + (size_t)BB * NN * DD;

    float* ws = (float*)d_ws;
    float* xn   = ws;                 // 98304
    float* Qb   = xn + 98304;
    float* Kx   = Qb + 98304;
    float* Vx   = Kx + 98304;
    float* xh   = Vx + 98304;
    float* accP = xh + 98304;         // 393216 (fallback, 4 splits)
    float* mP   = accP + 393216;      // 12288
    float* lP   = mP + 12288;         // 12288
    unsigned short* w1f  = (unsigned short*)(lP + 12288);   // 262144
    unsigned short* w2f  = w1f + 262144;                    // 262144
    unsigned short* WOef = w2f + 262144;                    // 65536
    unsigned short* Wqf  = WOef + 65536;                    // 65536
    unsigned short* Wkf  = Wqf + 65536;                     // 65536
    unsigned short* Wvf  = Wkf + 65536;                     // 65536
    float* accP3 = (float*)(Wvf + 65536);                   // 3*98304 = 294912
    float* mP3   = accP3 + 294912;                          // 9216
    float* lP3   = mP3 + 9216;                              // 9216

    const size_t NEED = 909312ull * 4 + 38453504ull * 2;
    bool mfma_path = ws_size >= NEED;

    dim3 blk(256);

    if (mfma_path) {
        k_prep_cvt<<<dim3(432), blk, 0, stream>>>(
            x, ln_x_g, ln_x_b, Wq_en, bq_en, Wk_ne, bk_ne, Wv_ne, bv_ne,
            xn, Qb, Kx, Vx,
            mlpe_w1, mlpe_w2, WOe_w, Wq_ne, Wk_en, Wv_en,
            w1f, w2f, WOef, Wqf, Wkf, Wvf);

        k_n2e_fused<<<dim3(NTILE3), dim3(512), 0, stream>>>(
            e, ln_e_g, ln_e_b, Wqf, bq_ne, Wkf, bk_en, Wvf, bv_en,
            Kx, Vx, Qb, WOef, WOe_b,
            ln_e2_g, ln_e2_b, w1f, mlpe_b1, w2f, mlpe_b2,
            out_e, accP3, mP3, lP3);

        k_x_epi3<<<dim3(BB * NN / 4), blk, 0, stream>>>(
            accP3, mP3, lP3, xn, WOx_w, WOx_b, ln_x2_g, ln_x2_b,
            mlpx_w1, mlpx_b1, mlpx_w2, mlpx_b2, out_x);
    } else {
        // fp32 fallback path
        k_node_prep<<<dim3(BB * NN / 8), blk, 0, stream>>>(
            x, ln_x_g, ln_x_b, Wq_en, bq_en, Wk_ne, bk_ne, Wv_ne, bv_ne,
            xn, Qb, Kx, Vx);

        k_n2e<<<dim3(BB * NN * (NN / 8)), blk, 0, stream>>>(
            e, ln_e_g, ln_e_b, Wq_ne, bq_ne, Kx, Vx, WOe_w, WOe_b, out_e);

        k_e2n_attn<<<dim3(BB * NN * SJ), blk, 0, stream>>>(
            e, ln_e_g, ln_e_b, Wk_en, bk_en, Wv_en, bv_en, Qb, accP, mP, lP);

        k_e2n_mergeN<<<dim3(BB * NN), blk, 0, stream>>>(accP, mP, lP, xh, SJ);

        k_x_epi<<<dim3(BB * NN / 8), blk, 0, stream>>>(
            xh, xn, WOx_w, WOx_b, ln_x2_g, ln_x2_b,
            mlpx_w1, mlpx_b1, mlpx_w2, mlpx_b2, out_x);

        k_e_mlp_f32<<<dim3(BB * NN * NN / 8), blk, 0, stream>>>(
            out_e, ln_e2_g, ln_e2_b, mlpe_w1, mlpe_b1, mlpe_w2, mlpe_b2);
    }
}

// Round 21
// 383.276 us; speedup vs baseline: 1.0736x; 1.0736x over previous
//
#include <hip/hip_runtime.h>
#include <hip/hip_bf16.h>
#include <math.h>

#define BB 2
#define NN 192
#define DD 256
#define HH 8
#define DHH 32
#define SCALE 0.17677669529663687f  // 1/sqrt(32)
#define SJ 4                         // j-splits (fallback path)
#define NS3 3                        // j-splits (fused path: 3 tiles of 64)
#define NTILE3 (BB * NN * 3)         // 1152 edge tiles of 64 rows

typedef __attribute__((ext_vector_type(8))) short short8;
typedef __attribute__((ext_vector_type(4))) float f32x4;

// ---------- helpers ----------

__device__ __forceinline__ float red32(float v) {
    v += __shfl_xor(v, 16);
    v += __shfl_xor(v, 8);
    v += __shfl_xor(v, 4);
    v += __shfl_xor(v, 2);
    v += __shfl_xor(v, 1);
    return v;
}

__device__ __forceinline__ float red64(float v) {
    v += __shfl_xor(v, 32);
    v += __shfl_xor(v, 16);
    v += __shfl_xor(v, 8);
    v += __shfl_xor(v, 4);
    v += __shfl_xor(v, 2);
    v += __shfl_xor(v, 1);
    return v;
}

__device__ __forceinline__ unsigned short f2bf(float f) {
    unsigned int u = __builtin_bit_cast(unsigned int, f);
    u += 0x7FFFu + ((u >> 16) & 1u);   // RNE
    return (unsigned short)(u >> 16);
}

__device__ __forceinline__ float bf2f(unsigned short u) {
    unsigned int v = ((unsigned int)u) << 16;
    return __builtin_bit_cast(float, v);
}

// LayerNorm 8 rows of [256] in-place in LDS. 256 threads.
__device__ __forceinline__ void ln8(float (*xs)[DD], const float* __restrict__ g,
                                    const float* __restrict__ b,
                                    float* mred, float* rred) {
    int t = threadIdx.x;
    int r = t >> 5, l = t & 31;
    float s = 0.f, s2 = 0.f;
#pragma unroll
    for (int u = 0; u < 8; u++) {
        float v = xs[r][l + 32 * u];
        s += v; s2 += v * v;
    }
    s = red32(s); s2 = red32(s2);
    if (l == 0) {
        float mean = s * (1.f / 256.f);
        float var  = s2 * (1.f / 256.f) - mean * mean;
        mred[r] = mean;
        rred[r] = rsqrtf(var + 1e-5f);
    }
    __syncthreads();
    float gt = g[t], bt = b[t];
#pragma unroll
    for (int rr = 0; rr < 8; rr++) {
        float v = xs[rr][t];
        xs[rr][t] = (v - mred[rr]) * rred[rr] * gt + bt;
    }
    __syncthreads();
}

// 256-col MFMA GEMM over a 64-row A-tile; each wave owns 32 output cols
// (2 tiles of 16), 4 m-tiles. Wf fragment-linear: tile id = w*2+nt (0..15).
__device__ __forceinline__ void gemm256m4(const unsigned short (*A)[264],
                                          const unsigned short* __restrict__ Wf,
                                          int w, int lane, int fr, int fq,
                                          f32x4 acc[4][2]) {
#pragma unroll
    for (int m = 0; m < 4; m++)
#pragma unroll
        for (int nt = 0; nt < 2; nt++) acc[m][nt] = (f32x4){0.f, 0.f, 0.f, 0.f};
    short8 nb[2];
#pragma unroll
    for (int nt = 0; nt < 2; nt++)
        nb[nt] = *(const short8*)(Wf + (((size_t)(w * 2 + nt) * 8 + 0) * 64 + lane) * 8);
#pragma unroll
    for (int k = 0; k < 8; k++) {
        short8 cb[2];
#pragma unroll
        for (int nt = 0; nt < 2; nt++) cb[nt] = nb[nt];
        if (k < 7) {
#pragma unroll
            for (int nt = 0; nt < 2; nt++)
                nb[nt] = *(const short8*)(Wf + (((size_t)(w * 2 + nt) * 8 + k + 1) * 64 + lane) * 8);
        }
        short8 av[4];
#pragma unroll
        for (int m = 0; m < 4; m++)
            av[m] = *(const short8*)&A[m * 16 + fr][k * 32 + fq * 8];
#pragma unroll
        for (int nt = 0; nt < 2; nt++)
#pragma unroll
            for (int m = 0; m < 4; m++)
                acc[m][nt] = __builtin_amdgcn_mfma_f32_16x16x32_bf16(av[m], cb[nt], acc[m][nt], 0, 0, 0);
    }
}

// ---------- kernel 1 (MERGED): node prep (blocks 0..47) + weight convert (48..431) ----------
__global__ void k_prep_cvt(const float* __restrict__ x,
                           const float* __restrict__ lnxg, const float* __restrict__ lnxb,
                           const float* __restrict__ Wq, const float* __restrict__ bq,
                           const float* __restrict__ Wk, const float* __restrict__ bk,
                           const float* __restrict__ Wv, const float* __restrict__ bv,
                           float* __restrict__ xn, float* __restrict__ Qb,
                           float* __restrict__ Kx, float* __restrict__ Vx,
                           const float* __restrict__ w1, const float* __restrict__ w2,
                           const float* __restrict__ WOe,
                           const float* __restrict__ Wqn, const float* __restrict__ Wke,
                           const float* __restrict__ Wve,
                           unsigned short* __restrict__ w1f, unsigned short* __restrict__ w2f,
                           unsigned short* __restrict__ WOef,
                           unsigned short* __restrict__ Wqf, unsigned short* __restrict__ Wkf,
                           unsigned short* __restrict__ Wvf) {
    int t = threadIdx.x;
    if (blockIdx.x < 48) {
        __shared__ float xs[8][DD];
        __shared__ float mred[8], rred[8];
        int r0 = blockIdx.x * 8;
        for (int r = 0; r < 8; r++) xs[r][t] = x[(r0 + r) * DD + t];
        __syncthreads();
        ln8(xs, lnxg, lnxb, mred, rred);
        for (int r = 0; r < 8; r++) xn[(r0 + r) * DD + t] = xs[r][t];
        int h = t >> 5, d_ = t & 31;
        const float* wq = Wq + h * DD * DHH + d_;
        const float* wk = Wk + h * DD * DHH + d_;
        const float* wv = Wv + h * DD * DHH + d_;
        float aq[8] = {0}, ak[8] = {0}, av[8] = {0};
        for (int k = 0; k < DD; k++) {
            float w1v = wq[k * DHH], w2v = wk[k * DHH], w3v = wv[k * DHH];
#pragma unroll
            for (int r = 0; r < 8; r++) {
                float ev = xs[r][k];
                aq[r] += ev * w1v; ak[r] += ev * w2v; av[r] += ev * w3v;
            }
        }
        float bqt = bq[t], bkt = bk[t], bvt = bv[t];
        for (int r = 0; r < 8; r++) {
            Qb[(r0 + r) * DD + t] = aq[r] + bqt;
            Kx[(r0 + r) * DD + t] = ak[r] + bkt;
            Vx[(r0 + r) * DD + t] = av[r] + bvt;
        }
        return;
    }
    int bid = blockIdx.x - 48;
    short8 out;
    if (bid < 128) {
        int fi = bid * 256 + t;            // fragment index, 32768 total
        int l = fi & 63, g = fi >> 6;      // g = tau*8 + kap, tau<64
        int fr = l & 15, fq = l >> 4;
        int tau = g >> 3, kap = g & 7;
        const float* src = w1 + (size_t)(tau * 16 + fr) * 256 + kap * 32 + fq * 8;
#pragma unroll
        for (int u = 0; u < 8; u++) out[u] = (short)f2bf(src[u]);
        *(short8*)(w1f + (size_t)fi * 8) = out;
    } else if (bid < 256) {
        int fi = (bid - 128) * 256 + t;
        int l = fi & 63, g = fi >> 6;      // g = tau2*32 + kap2, tau2<16
        int fr = l & 15, fq = l >> 4;
        int tau = g >> 5, kap = g & 31;
        const float* src = w2 + (size_t)(tau * 16 + fr) * 1024 + kap * 32 + fq * 8;
#pragma unroll
        for (int u = 0; u < 8; u++) out[u] = (short)f2bf(src[u]);
        *(short8*)(w2f + (size_t)fi * 8) = out;
    } else if (bid < 288) {
        int fi = (bid - 256) * 256 + t;    // 8192 frags
        int l = fi & 63, g = fi >> 6;
        int fr = l & 15, fq = l >> 4;
        int tau = g >> 3, kap = g & 7;
        const float* src = WOe + (size_t)(tau * 16 + fr) * 256 + kap * 32 + fq * 8;
#pragma unroll
        for (int u = 0; u < 8; u++) out[u] = (short)f2bf(src[u]);
        *(short8*)(WOef + (size_t)fi * 8) = out;
    } else {
        int which = (bid - 288) >> 5;      // 0=Wq 1=Wk 2=Wv
        int fi = ((bid - 288) & 31) * 256 + t;
        int l = fi & 63, g = fi >> 6;
        int fr = l & 15, fq = l >> 4;
        int tau = g >> 3, kap = g & 7;
        int n = tau * 16 + fr;
        int k0 = kap * 32 + fq * 8;
        const float* src = which == 0 ? Wqn : which == 1 ? Wke : Wve;
        const float* s2 = src + (size_t)(n >> 5) * 8192 + (n & 31);
#pragma unroll
        for (int u = 0; u < 8; u++) out[u] = (short)f2bf(s2[(size_t)(k0 + u) * 32]);
        unsigned short* dst = which == 0 ? Wqf : which == 1 ? Wkf : Wvf;
        *(short8*)(dst + (size_t)fi * 8) = out;
    }
}

// ---------- kernel 2 (FUSED, M=64): n2e attn + WOe + resid + LN2 + e-MLP
//            + e2n attention PARTIAL. grid 1152, block 512 = 8 waves. ----------
__global__ __launch_bounds__(512, 2) void k_n2e_fused(
    const float* __restrict__ e,
    const float* __restrict__ lneg, const float* __restrict__ lneb,
    const unsigned short* __restrict__ Wqf, const float* __restrict__ bq,
    const unsigned short* __restrict__ Wkf, const float* __restrict__ bk,
    const unsigned short* __restrict__ Wvf, const float* __restrict__ bv,
    const float* __restrict__ Kx, const float* __restrict__ Vx,
    const float* __restrict__ Qb,
    const unsigned short* __restrict__ WOef, const float* __restrict__ WOb,
    const float* __restrict__ ln2g, const float* __restrict__ ln2b,
    const unsigned short* __restrict__ w1f, const float* __restrict__ b1,
    const unsigned short* __restrict__ w2f, const float* __restrict__ b2,
    float* __restrict__ oute,
    float* __restrict__ accP3, float* __restrict__ mP3, float* __restrict__ lP3) {
    __shared__ unsigned short a_bf[64][264];   // LN(e) tile -> later h tile
    __shared__ unsigned short p_bf[64][264];   // e_heads -> later LN2 A-tile
    __shared__ float KxiS[DD], VxiS[DD], QbS[DD];
    __shared__ float mrow[64], rrow[64];
    __shared__ float sW[64][8], s2W[64][8];
    __shared__ float m2s[64], r2s[64];
    int t = threadIdx.x, lane = t & 63, w = t >> 6;   // 8 waves
    int fr = lane & 15, fq = lane >> 4;
    int blk = blockIdx.x;
    int b   = blk / (NN * 3);
    int rem = blk % (NN * 3);
    int i   = rem / 3;
    int spl = rem % 3;
    int j0  = spl * 64;
    int node = b * NN + i;
    size_t ebase = ((size_t)node * NN + j0) * DD;

    // ---- LN of 64 rows -> a_bf (bf16); keep mean/rstd. 8 thr/row, 32 cols each.
    {
        int r = t >> 3, sub = t & 7;
        const float4* src4 = (const float4*)(e + ebase + (size_t)r * DD + sub * 32);
        float vals[32];
        float s = 0.f, s2 = 0.f;
#pragma unroll
        for (int u = 0; u < 8; u++) {
            float4 v = src4[u];
            vals[4 * u + 0] = v.x; vals[4 * u + 1] = v.y;
            vals[4 * u + 2] = v.z; vals[4 * u + 3] = v.w;
            s += v.x + v.y + v.z + v.w;
            s2 += v.x * v.x + v.y * v.y + v.z * v.z + v.w * v.w;
        }
        s += __shfl_xor(s, 4); s2 += __shfl_xor(s2, 4);
        s += __shfl_xor(s, 2); s2 += __shfl_xor(s2, 2);
        s += __shfl_xor(s, 1); s2 += __shfl_xor(s2, 1);
        float mean = s * (1.f / 256.f);
        float rstd = rsqrtf(s2 * (1.f / 256.f) - mean * mean + 1e-5f);
        if (sub == 0) { mrow[r] = mean; rrow[r] = rstd; }
#pragma unroll
        for (int u = 0; u < 32; u += 2) {
            int col = sub * 32 + u;
            float n0 = (vals[u]     - mean) * rstd * lneg[col]     + lneb[col];
            float n1 = (vals[u + 1] - mean) * rstd * lneg[col + 1] + lneb[col + 1];
            unsigned int pk = (unsigned int)f2bf(n0) | ((unsigned int)f2bf(n1) << 16);
            *(unsigned int*)&a_bf[r][col] = pk;
        }
    }
    if (t < DD) {
        KxiS[t] = Kx[node * DD + t];
        VxiS[t] = Vx[node * DD + t];
        QbS[t]  = Qb[node * DD + t];
    }
    __syncthreads();

    const int nw = w * 32;   // this wave's 32-col slice = head w

    // ---- GEMM: K_en (keep in regs, bias included)
    f32x4 accK[4][2];
    gemm256m4(a_bf, Wkf, w, lane, fr, fq, accK);
#pragma unroll
    for (int nt = 0; nt < 2; nt++) {
        float bb = bk[nw + nt * 16 + fr];
#pragma unroll
        for (int m = 0; m < 4; m++)
#pragma unroll
            for (int j = 0; j < 4; j++) accK[m][nt][j] += bb;
    }

    // ---- GEMM: V_en (keep in regs, bias included)
    f32x4 accV[4][2];
    gemm256m4(a_bf, Wvf, w, lane, fr, fq, accV);
#pragma unroll
    for (int nt = 0; nt < 2; nt++) {
        float bb = bv[nw + nt * 16 + fr];
#pragma unroll
        for (int m = 0; m < 4; m++)
#pragma unroll
            for (int j = 0; j < 4; j++) accV[m][nt][j] += bb;
    }

    // ---- e2n attention PARTIAL over this block's 64 j-rows (split spl)
    {
        float QbL[2];
        QbL[0] = QbS[nw + fr];
        QbL[1] = QbS[nw + 16 + fr];
        float p[4][4];
        float mx = -1e30f;
#pragma unroll
        for (int m = 0; m < 4; m++)
#pragma unroll
            for (int j = 0; j < 4; j++) {
                float s = accK[m][0][j] * QbL[0] + accK[m][1][j] * QbL[1];
                s += __shfl_xor(s, 1);
                s += __shfl_xor(s, 2);
                s += __shfl_xor(s, 4);
                s += __shfl_xor(s, 8);
                s *= SCALE;
                p[m][j] = s;
                mx = fmaxf(mx, s);
            }
        mx = fmaxf(mx, __shfl_xor(mx, 16));
        mx = fmaxf(mx, __shfl_xor(mx, 32));
        float lsum = 0.f;
#pragma unroll
        for (int m = 0; m < 4; m++)
#pragma unroll
            for (int j = 0; j < 4; j++) {
                p[m][j] = __expf(p[m][j] - mx);
                lsum += p[m][j];
            }
        lsum += __shfl_xor(lsum, 16);
        lsum += __shfl_xor(lsum, 32);
        float part[2];
#pragma unroll
        for (int nt = 0; nt < 2; nt++) {
            float acc = 0.f;
#pragma unroll
            for (int m = 0; m < 4; m++)
#pragma unroll
                for (int j = 0; j < 4; j++)
                    acc += p[m][j] * accV[m][nt][j];
            acc += __shfl_xor(acc, 16);
            acc += __shfl_xor(acc, 32);
            part[nt] = acc;
        }
        if (fq == 0) {
#pragma unroll
            for (int nt = 0; nt < 2; nt++)
                accP3[((size_t)spl * BB * NN + node) * DD + nw + nt * 16 + fr] = part[nt];
            if (fr == 0) {
                mP3[((size_t)spl * BB * NN + node) * HH + w] = mx;
                lP3[((size_t)spl * BB * NN + node) * HH + w] = lsum;
            }
        }
    }

    // ---- GEMM: Qe
    f32x4 accQ[4][2];
    gemm256m4(a_bf, Wqf, w, lane, fr, fq, accQ);
    {
        float bqv[2];
#pragma unroll
        for (int nt = 0; nt < 2; nt++) bqv[nt] = bq[nw + nt * 16 + fr];
#pragma unroll
        for (int m = 0; m < 4; m++)
#pragma unroll
            for (int nt = 0; nt < 2; nt++)
#pragma unroll
                for (int j = 0; j < 4; j++) accQ[m][nt][j] += bqv[nt];
    }

    // ---- n2e scores: si = Qe . Kx[i], sj = Qe . Kx[j]; softmax over {i,j}
    float KxiL[2], VxiL[2];
#pragma unroll
    for (int nt = 0; nt < 2; nt++) {
        KxiL[nt] = KxiS[nw + nt * 16 + fr];
        VxiL[nt] = VxiS[nw + nt * 16 + fr];
    }
    float ai[4][4], aj[4][4];   // [m][j] (one head per wave)
#pragma unroll
    for (int m = 0; m < 4; m++)
#pragma unroll
        for (int j = 0; j < 4; j++) {
            int row = m * 16 + fq * 4 + j;
            float k0v = Kx[(size_t)(b * NN + j0 + row) * DD + nw + fr];
            float k1v = Kx[(size_t)(b * NN + j0 + row) * DD + nw + 16 + fr];
            float p = accQ[m][0][j] * KxiL[0] + accQ[m][1][j] * KxiL[1];
            float q = accQ[m][0][j] * k0v + accQ[m][1][j] * k1v;
#pragma unroll
            for (int mk = 1; mk <= 8; mk <<= 1) {
                p += __shfl_xor(p, mk);
                q += __shfl_xor(q, mk);
            }
            p *= SCALE; q *= SCALE;
            float mx = fmaxf(p, q);
            float ei = __expf(p - mx), ej = __expf(q - mx);
            float inv = 1.f / (ei + ej);
            ai[m][j] = ei * inv; aj[m][j] = ej * inv;
        }
    // ---- e_heads = ai*Vx[i] + aj*Vx[j] -> p_bf
#pragma unroll
    for (int m = 0; m < 4; m++)
#pragma unroll
        for (int j = 0; j < 4; j++) {
            int row = m * 16 + fq * 4 + j;
            float v0 = Vx[(size_t)(b * NN + j0 + row) * DD + nw + fr];
            float v1 = Vx[(size_t)(b * NN + j0 + row) * DD + nw + 16 + fr];
            p_bf[row][nw + fr]      = f2bf(ai[m][j] * VxiL[0] + aj[m][j] * v0);
            p_bf[row][nw + 16 + fr] = f2bf(ai[m][j] * VxiL[1] + aj[m][j] * v1);
        }
    __syncthreads();

    // ---- GEMM: e_heads @ WOe^T
    f32x4 accO[4][2];
    gemm256m4(p_bf, WOef, w, lane, fr, fq, accO);

    // ---- epre = fp32 LN1 residual + accO + bo  (kept in registers)
    float epre[4][2][4];
#pragma unroll
    for (int nt = 0; nt < 2; nt++) {
        int col = nw + nt * 16 + fr;
        float bo = WOb[col];
        float gc = lneg[col], bc = lneb[col];
#pragma unroll
        for (int m = 0; m < 4; m++)
#pragma unroll
            for (int j = 0; j < 4; j++) {
                int row = m * 16 + fq * 4 + j;
                float ev = e[ebase + (size_t)row * DD + col];
                float resid = (ev - mrow[row]) * rrow[row] * gc + bc;
                epre[m][nt][j] = resid + accO[m][nt][j] + bo;
            }
    }

    // ---- LN2 stats (cross-lane over fr, cross-wave via LDS)
#pragma unroll
    for (int m = 0; m < 4; m++)
#pragma unroll
        for (int j = 0; j < 4; j++) {
            float s  = epre[m][0][j] + epre[m][1][j];
            float s2 = epre[m][0][j] * epre[m][0][j] + epre[m][1][j] * epre[m][1][j];
#pragma unroll
            for (int mk = 1; mk <= 8; mk <<= 1) {
                s += __shfl_xor(s, mk);
                s2 += __shfl_xor(s2, mk);
            }
            if (fr == 0) {
                int row = m * 16 + fq * 4 + j;
                sW[row][w] = s;
                s2W[row][w] = s2;
            }
        }
    __syncthreads();   // all reads of p_bf (WOe GEMM) done -> safe to overwrite
    if (t < 64) {
        float S = 0.f, S2 = 0.f;
#pragma unroll
        for (int ww = 0; ww < 8; ww++) { S += sW[t][ww]; S2 += s2W[t][ww]; }
        float mean = S * (1.f / 256.f);
        float var  = S2 * (1.f / 256.f) - mean * mean;
        m2s[t] = mean;
        r2s[t] = rsqrtf(var + 1e-5f);
    }
    __syncthreads();

    // ---- LN2(epre) bf16 -> p_bf (MLP A-tile)
#pragma unroll
    for (int nt = 0; nt < 2; nt++) {
        int col = nw + nt * 16 + fr;
        float g2 = ln2g[col], b2c = ln2b[col];
#pragma unroll
        for (int m = 0; m < 4; m++)
#pragma unroll
            for (int j = 0; j < 4; j++) {
                int row = m * 16 + fq * 4 + j;
                p_bf[row][col] = f2bf((epre[m][nt][j] - m2s[row]) * r2s[row] * g2 + b2c);
            }
    }
    __syncthreads();

    // ---- e-MLP: A = p_bf, h -> a_bf (reuse), accumulate accM
#define B1ADDR(c, nt, k) (w1f + (((size_t)((c) * 16 + w * 2 + (nt)) * 8 + (k)) * 64 + lane) * 8)
#define B2ADDR(nt, c, k) (w2f + (((size_t)(w * 2 + (nt)) * 32 + (c) * 8 + (k)) * 64 + lane) * 8)
    f32x4 accM[4][2];
#pragma unroll
    for (int m = 0; m < 4; m++)
#pragma unroll
        for (int nt = 0; nt < 2; nt++) accM[m][nt] = (f32x4){0.f, 0.f, 0.f, 0.f};

    for (int c = 0; c < 4; c++) {
        f32x4 acc1[4][2];
#pragma unroll
        for (int m = 0; m < 4; m++)
#pragma unroll
            for (int nt = 0; nt < 2; nt++) acc1[m][nt] = (f32x4){0.f, 0.f, 0.f, 0.f};
        {
            short8 nb[2];
#pragma unroll
            for (int nt = 0; nt < 2; nt++) nb[nt] = *(const short8*)B1ADDR(c, nt, 0);
#pragma unroll
            for (int k = 0; k < 8; k++) {
                short8 cb[2];
#pragma unroll
                for (int nt = 0; nt < 2; nt++) cb[nt] = nb[nt];
                if (k < 7) {
#pragma unroll
                    for (int nt = 0; nt < 2; nt++) nb[nt] = *(const short8*)B1ADDR(c, nt, k + 1);
                }
                short8 av[4];
#pragma unroll
                for (int m = 0; m < 4; m++)
                    av[m] = *(const short8*)&p_bf[m * 16 + fr][k * 32 + fq * 8];
#pragma unroll
                for (int nt = 0; nt < 2; nt++)
#pragma unroll
                    for (int m = 0; m < 4; m++)
                        acc1[m][nt] = __builtin_amdgcn_mfma_f32_16x16x32_bf16(av[m], cb[nt], acc1[m][nt], 0, 0, 0);
            }
        }
#pragma unroll
        for (int nt = 0; nt < 2; nt++) {
            int ncol = nw + nt * 16 + fr;
            float bias = b1[c * 256 + ncol];
#pragma unroll
            for (int m = 0; m < 4; m++)
#pragma unroll
                for (int j = 0; j < 4; j++) {
                    float v = acc1[m][nt][j] + bias;
                    v = v > 0.f ? v : 0.01f * v;
                    a_bf[m * 16 + fq * 4 + j][ncol] = f2bf(v);
                }
        }
        __syncthreads();
        {
            short8 nb[2];
#pragma unroll
            for (int nt = 0; nt < 2; nt++) nb[nt] = *(const short8*)B2ADDR(nt, c, 0);
#pragma unroll
            for (int k = 0; k < 8; k++) {
                short8 cb[2];
#pragma unroll
                for (int nt = 0; nt < 2; nt++) cb[nt] = nb[nt];
                if (k < 7) {
#pragma unroll
                    for (int nt = 0; nt < 2; nt++) nb[nt] = *(const short8*)B2ADDR(nt, c, k + 1);
                }
                short8 hv[4];
#pragma unroll
                for (int m = 0; m < 4; m++)
                    hv[m] = *(const short8*)&a_bf[m * 16 + fr][k * 32 + fq * 8];
#pragma unroll
                for (int nt = 0; nt < 2; nt++)
#pragma unroll
                    for (int m = 0; m < 4; m++)
                        accM[m][nt] = __builtin_amdgcn_mfma_f32_16x16x32_bf16(hv[m], cb[nt], accM[m][nt], 0, 0, 0);
            }
        }
        __syncthreads();   // protect a_bf before next chunk's h writes
    }
#undef B1ADDR
#undef B2ADDR

    // ---- final: e_out = epre + mlp + b2
#pragma unroll
    for (int nt = 0; nt < 2; nt++) {
        int col = nw + nt * 16 + fr;
        float bias = b2[col];
#pragma unroll
        for (int m = 0; m < 4; m++)
#pragma unroll
            for (int j = 0; j < 4; j++) {
                int row = m * 16 + fq * 4 + j;
                oute[ebase + (size_t)row * DD + col] = epre[m][nt][j] + accM[m][nt][j] + bias;
            }
    }
}

// ---------- merge kernel, parameterized split count (fallback path) ----------
__global__ void k_e2n_mergeN(const float* __restrict__ accP, const float* __restrict__ mP,
                             const float* __restrict__ lP, float* __restrict__ xh,
                             int nsplit) {
    int t = threadIdx.x, row = blockIdx.x, h = t >> 5;
    float m = -1e30f;
    for (int s = 0; s < nsplit; s++) m = fmaxf(m, mP[(s * BB * NN + row) * HH + h]);
    float num = 0.f, den = 0.f;
    for (int s = 0; s < nsplit; s++) {
        float c = __expf(mP[(s * BB * NN + row) * HH + h] - m);
        num += accP[((size_t)s * BB * NN + row) * DD + t] * c;
        den += lP[(s * BB * NN + row) * HH + h] * c;
    }
    xh[row * DD + t] = num / den;
}

// ---------- kernel 4 (MERGED, 4 rows/block): 3-split e2n merge + WOx + resid + LN2 + MLP ----------
// grid 96 (BB*NN/4) for better CU coverage; one wave per row in LN stats.
__global__ void k_x_epi3(const float* __restrict__ accP3, const float* __restrict__ mP3,
                         const float* __restrict__ lP3,
                         const float* __restrict__ xn,
                         const float* __restrict__ WO, const float* __restrict__ WOb,
                         const float* __restrict__ ln2g, const float* __restrict__ ln2b,
                         const float* __restrict__ w1, const float* __restrict__ b1,
                         const float* __restrict__ w2, const float* __restrict__ b2,
                         float* __restrict__ outx) {
    __shared__ float hsrc[4][DD];
    __shared__ float xs[4][DD];
    __shared__ float ls[4][DD];
    __shared__ float hh[4][1024];
    __shared__ float mred[4], rred[4];
    int t = threadIdx.x;
    int r0 = blockIdx.x * 4;
    int h = t >> 5;
    // inline 3-split merge -> hsrc
    for (int r = 0; r < 4; r++) {
        int row = r0 + r;
        float m = -1e30f;
#pragma unroll
        for (int s = 0; s < NS3; s++) m = fmaxf(m, mP3[(s * BB * NN + row) * HH + h]);
        float num = 0.f, den = 0.f;
#pragma unroll
        for (int s = 0; s < NS3; s++) {
            float c = __expf(mP3[(s * BB * NN + row) * HH + h] - m);
            num += accP3[((size_t)s * BB * NN + row) * DD + t] * c;
            den += lP3[(s * BB * NN + row) * HH + h] * c;
        }
        hsrc[r][t] = num / den;
    }
    __syncthreads();
    float acc[4] = {0};
    const float* wrow = WO + (size_t)t * DD;
    for (int k = 0; k < DD; k++) {
        float w = wrow[k];
#pragma unroll
        for (int r = 0; r < 4; r++) acc[r] += hsrc[r][k] * w;
    }
    float wob = WOb[t];
    for (int r = 0; r < 4; r++) {
        float v = xn[(r0 + r) * DD + t] + acc[r] + wob;
        xs[r][t] = v;
        ls[r][t] = v;
    }
    __syncthreads();
    // LN: one wave per row (r = t>>6, l = t&63, each lane sums 4 cols)
    {
        int r = t >> 6, l = t & 63;
        float s = 0.f, s2 = 0.f;
#pragma unroll
        for (int u = 0; u < 4; u++) {
            float v = ls[r][l + 64 * u];
            s += v; s2 += v * v;
        }
        s = red64(s); s2 = red64(s2);
        if (l == 0) {
            float mean = s * (1.f / 256.f);
            float var  = s2 * (1.f / 256.f) - mean * mean;
            mred[r] = mean;
            rred[r] = rsqrtf(var + 1e-5f);
        }
    }
    __syncthreads();
    {
        float gt = ln2g[t], bt = ln2b[t];
#pragma unroll
        for (int rr = 0; rr < 4; rr++) {
            float v = ls[rr][t];
            ls[rr][t] = (v - mred[rr]) * rred[rr] * gt + bt;
        }
    }
    __syncthreads();
    for (int p = 0; p < 4; p++) {
        int q = t + p * 256;
        float a2[4] = {0};
        const float* w1r = w1 + (size_t)q * DD;
        for (int k = 0; k < DD; k++) {
            float w = w1r[k];
#pragma unroll
            for (int r = 0; r < 4; r++) a2[r] += ls[r][k] * w;
        }
        float b1q = b1[q];
        for (int r = 0; r < 4; r++) {
            float v = a2[r] + b1q;
            hh[r][q] = v > 0.f ? v : 0.01f * v;
        }
    }
    __syncthreads();
    float a3[4] = {0};
    const float* w2r = w2 + (size_t)t * 1024;
    for (int q = 0; q < 1024; q++) {
        float w = w2r[q];
#pragma unroll
        for (int r = 0; r < 4; r++) a3[r] += hh[r][q] * w;
    }
    float b2t = b2[t];
    for (int r = 0; r < 4; r++)
        outx[(r0 + r) * DD + t] = xs[r][t] + a3[r] + b2t;
}

// ---------- kernel 4 (fallback): x epilogue reading xh ----------
__global__ void k_x_epi(const float* __restrict__ xh, const float* __restrict__ xn,
                        const float* __restrict__ WO, const float* __restrict__ WOb,
                        const float* __restrict__ ln2g, const float* __restrict__ ln2b,
                        const float* __restrict__ w1, const float* __restrict__ b1,
                        const float* __restrict__ w2, const float* __restrict__ b2,
                        float* __restrict__ outx) {
    __shared__ float hsrc[8][DD];
    __shared__ float xs[8][DD];
    __shared__ float ls[8][DD];
    __shared__ float hh[8][1024];
    __shared__ float mred[8], rred[8];
    int t = threadIdx.x;
    int r0 = blockIdx.x * 8;
    for (int r = 0; r < 8; r++) hsrc[r][t] = xh[(r0 + r) * DD + t];
    __syncthreads();
    float acc[8] = {0};
    const float* wrow = WO + (size_t)t * DD;
    for (int k = 0; k < DD; k++) {
        float w = wrow[k];
#pragma unroll
        for (int r = 0; r < 8; r++) acc[r] += hsrc[r][k] * w;
    }
    float wob = WOb[t];
    for (int r = 0; r < 8; r++) {
        float v = xn[(r0 + r) * DD + t] + acc[r] + wob;
        xs[r][t] = v;
        ls[r][t] = v;
    }
    __syncthreads();
    ln8(ls, ln2g, ln2b, mred, rred);
    for (int p = 0; p < 4; p++) {
        int q = t + p * 256;
        float a2[8] = {0};
        const float* w1r = w1 + (size_t)q * DD;
        for (int k = 0; k < DD; k++) {
            float w = w1r[k];
#pragma unroll
            for (int r = 0; r < 8; r++) a2[r] += ls[r][k] * w;
        }
        float b1q = b1[q];
        for (int r = 0; r < 8; r++) {
            float v = a2[r] + b1q;
            hh[r][q] = v > 0.f ? v : 0.01f * v;
        }
    }
    __syncthreads();
    float a3[8] = {0};
    const float* w2r = w2 + (size_t)t * 1024;
    for (int q = 0; q < 1024; q++) {
        float w = w2r[q];
#pragma unroll
        for (int r = 0; r < 8; r++) a3[r] += hh[r][q] * w;
    }
    float b2t = b2[t];
    for (int r = 0; r < 8; r++)
        outx[(r0 + r) * DD + t] = xs[r][t] + a3[r] + b2t;
}

// ---------- FALLBACK kernels (fp32, used only if ws too small) ----------
__global__ void k_node_prep(const float* __restrict__ x,
                            const float* __restrict__ lnxg, const float* __restrict__ lnxb,
                            const float* __restrict__ Wq, const float* __restrict__ bq,
                            const float* __restrict__ Wk, const float* __restrict__ bk,
                            const float* __restrict__ Wv, const float* __restrict__ bv,
                            float* __restrict__ xn, float* __restrict__ Qb,
                            float* __restrict__ Kx, float* __restrict__ Vx) {
    __shared__ float xs[8][DD];
    __shared__ float mred[8], rred[8];
    int t = threadIdx.x;
    int r0 = blockIdx.x * 8;
    for (int r = 0; r < 8; r++) xs[r][t] = x[(r0 + r) * DD + t];
    __syncthreads();
    ln8(xs, lnxg, lnxb, mred, rred);
    for (int r = 0; r < 8; r++) xn[(r0 + r) * DD + t] = xs[r][t];
    int h = t >> 5, d_ = t & 31;
    const float* wq = Wq + h * DD * DHH + d_;
    const float* wk = Wk + h * DD * DHH + d_;
    const float* wv = Wv + h * DD * DHH + d_;
    float aq[8] = {0}, ak[8] = {0}, av[8] = {0};
    for (int k = 0; k < DD; k++) {
        float w1 = wq[k * DHH], w2 = wk[k * DHH], w3 = wv[k * DHH];
#pragma unroll
        for (int r = 0; r < 8; r++) {
            float e = xs[r][k];
            aq[r] += e * w1; ak[r] += e * w2; av[r] += e * w3;
        }
    }
    float bqt = bq[t], bkt = bk[t], bvt = bv[t];
    for (int r = 0; r < 8; r++) {
        Qb[(r0 + r) * DD + t] = aq[r] + bqt;
        Kx[(r0 + r) * DD + t] = ak[r] + bkt;
        Vx[(r0 + r) * DD + t] = av[r] + bvt;
    }
}

__global__ void k_e2n_attn(const float* __restrict__ e,
                           const float* __restrict__ lneg, const float* __restrict__ lneb,
                           const float* __restrict__ Wk, const float* __restrict__ bk,
                           const float* __restrict__ Wv, const float* __restrict__ bv,
                           const float* __restrict__ Qb,
                           float* __restrict__ accP, float* __restrict__ mP,
                           float* __restrict__ lP) {
    __shared__ float es[8][DD];
    __shared__ float mred[8], rred[8];
    int t = threadIdx.x;
    int s = blockIdx.x & (SJ - 1);
    int row = blockIdx.x >> 2;
    int h = t >> 5, d_ = t & 31;
    float qt = Qb[row * DD + t];
    float m_s = -1e30f, l_s = 0.f, acc = 0.f;
    const float* wk = Wk + h * DD * DHH + d_;
    const float* wv = Wv + h * DD * DHH + d_;
    float bkt = bk[t], bvt = bv[t];
    for (int j0 = s * (NN / SJ); j0 < (s + 1) * (NN / SJ); j0 += 8) {
        for (int r = 0; r < 8; r++)
            es[r][t] = e[((size_t)row * NN + j0 + r) * DD + t];
        __syncthreads();
        ln8(es, lneg, lneb, mred, rred);
        float aK[8] = {0}, aV[8] = {0};
        for (int k = 0; k < DD; k++) {
            float w1 = wk[k * DHH], w2 = wv[k * DHH];
#pragma unroll
            for (int r = 0; r < 8; r++) {
                float ev = es[r][k];
                aK[r] += ev * w1; aV[r] += ev * w2;
            }
        }
#pragma unroll
        for (int r = 0; r < 8; r++) {
            float sc = red32(qt * (aK[r] + bkt)) * SCALE;
            float vn = aV[r] + bvt;
            float mn = fmaxf(m_s, sc);
            float c = __expf(m_s - mn);
            float p = __expf(sc - mn);
            l_s = l_s * c + p;
            acc = acc * c + p * vn;
            m_s = mn;
        }
        __syncthreads();
    }
    accP[((size_t)s * BB * NN + row) * DD + t] = acc;
    if (d_ == 0) {
        mP[(s * BB * NN + row) * HH + h] = m_s;
        lP[(s * BB * NN + row) * HH + h] = l_s;
    }
}

__global__ void k_n2e(const float* __restrict__ e,
                      const float* __restrict__ lneg, const float* __restrict__ lneb,
                      const float* __restrict__ Wq, const float* __restrict__ bq,
                      const float* __restrict__ Kx, const float* __restrict__ Vx,
                      const float* __restrict__ WO, const float* __restrict__ WOb,
                      float* __restrict__ oute) {
    __shared__ float es[8][DD];
    __shared__ float hs[8][DD];
    __shared__ float mred[8], rred[8];
    int t = threadIdx.x, h = t >> 5, d_ = t & 31;
    int blk = blockIdx.x;
    int b = blk / (NN * (NN / 8));
    int rem = blk % (NN * (NN / 8));
    int i = rem / (NN / 8);
    int j0 = (rem % (NN / 8)) * 8;
    size_t ebase = ((size_t)(b * NN + i) * NN + j0) * DD;
    for (int r = 0; r < 8; r++) es[r][t] = e[ebase + (size_t)r * DD + t];
    __syncthreads();
    ln8(es, lneg, lneb, mred, rred);
    float aQ[8] = {0};
    const float* wq = Wq + h * DD * DHH + d_;
    for (int k = 0; k < DD; k++) {
        float w = wq[k * DHH];
#pragma unroll
        for (int r = 0; r < 8; r++) aQ[r] += es[r][k] * w;
    }
    float bqt = bq[t];
    float kxi = Kx[(b * NN + i) * DD + t];
    float vxi = Vx[(b * NN + i) * DD + t];
#pragma unroll
    for (int r = 0; r < 8; r++) {
        float qe = aQ[r] + bqt;
        float si = red32(qe * kxi) * SCALE;
        float kxj = Kx[(b * NN + j0 + r) * DD + t];
        float sj = red32(qe * kxj) * SCALE;
        float mx = fmaxf(si, sj);
        float ei = __expf(si - mx), ej = __expf(sj - mx);
        float inv = 1.f / (ei + ej);
        float vxj = Vx[(b * NN + j0 + r) * DD + t];
        hs[r][t] = (ei * inv) * vxi + (ej * inv) * vxj;
    }
    __syncthreads();
    float aO[8] = {0};
    const float* wrow = WO + (size_t)t * DD;
    for (int k = 0; k < DD; k++) {
        float w = wrow[k];
#pragma unroll
        for (int r = 0; r < 8; r++) aO[r] += hs[r][k] * w;
    }
    float wob = WOb[t];
    for (int r = 0; r < 8; r++)
        oute[ebase + (size_t)r * DD + t] = es[r][t] + aO[r] + wob;
}

// ---------- fp32 e-MLP fallback ----------
__global__ void k_e_mlp_f32(float* __restrict__ oute,
                            const float* __restrict__ ln2g, const float* __restrict__ ln2b,
                            const float* __restrict__ w1, const float* __restrict__ b1,
                            const float* __restrict__ w2, const float* __restrict__ b2) {
    __shared__ float xs[8][DD];
    __shared__ float ls[8][DD];
    __shared__ float hh[8][1024];
    __shared__ float mred[8], rred[8];
    int t = threadIdx.x;
    size_t r0 = (size_t)blockIdx.x * 8;
    for (int r = 0; r < 8; r++) {
        float v = oute[(r0 + r) * DD + t];
        xs[r][t] = v;
        ls[r][t] = v;
    }
    __syncthreads();
    ln8(ls, ln2g, ln2b, mred, rred);
    for (int p = 0; p < 4; p++) {
        int q = t + p * 256;
        float a2[8] = {0};
        const float* w1r = w1 + (size_t)q * DD;
        for (int k = 0; k < DD; k++) {
            float w = w1r[k];
#pragma unroll
            for (int r = 0; r < 8; r++) a2[r] += ls[r][k] * w;
        }
        float b1q = b1[q];
        for (int r = 0; r < 8; r++) {
            float v = a2[r] + b1q;
            hh[r][q] = v > 0.f ? v : 0.01f * v;
        }
    }
    __syncthreads();
    float a3[8] = {0};
    const float* w2r = w2 + (size_t)t * 1024;
    for (int q = 0; q < 1024; q++) {
        float w = w2r[q];
#pragma unroll
        for (int r = 0; r < 8; r++) a3[r] += hh[r][q] * w;
    }
    float b2t = b2[t];
    for (int r = 0; r < 8; r++)
        oute[(r0 + r) * DD + t] = xs[r][t] + a3[r] + b2t;
}

// ---------- launch ----------
extern "C" void kernel_launch(void* const* d_in, const int* in_sizes, int n_in,
                              void* d_out, int out_size, void* d_ws, size_t ws_size,
                              hipStream_t stream) {
    (void)in_sizes; (void)n_in; (void)out_size;
    const float* x      = (const float*)d_in[0];
    const float* e      = (const float*)d_in[1];
    const float* ln_x_g = (const float*)d_in[2];
    const float* ln_x_b = (const float*)d_in[3];
    const float* ln_e_g = (const float*)d_in[4];
    const float* ln_e_b = (const float*)d_in[5];
    const float* ln_x2_g = (const float*)d_in[6];
    const float* ln_x2_b = (const float*)d_in[7];
    const float* ln_e2_g = (const float*)d_in[8];
    const float* ln_e2_b = (const float*)d_in[9];
    const float* Wq_en = (const float*)d_in[10];
    const float* bq_en = (const float*)d_in[11];
    const float* Wk_en = (const float*)d_in[12];
    const float* bk_en = (const float*)d_in[13];
    const float* Wv_en = (const float*)d_in[14];
    const float* bv_en = (const float*)d_in[15];
    const float* Wq_ne = (const float*)d_in[16];
    const float* bq_ne = (const float*)d_in[17];
    const float* Wk_ne = (const float*)d_in[18];
    const float* bk_ne = (const float*)d_in[19];
    const float* Wv_ne = (const float*)d_in[20];
    const float* bv_ne = (const float*)d_in[21];
    const float* WOx_w = (const float*)d_in[22];
    const float* WOx_b = (const float*)d_in[23];
    const float* WOe_w = (const float*)d_in[24];
    const float* WOe_b = (const float*)d_in[25];
    const float* mlpx_w1 = (const float*)d_in[26];
    const float* mlpx_b1 = (const float*)d_in[27];
    const float* mlpx_w2 = (const float*)d_in[28];
    const float* mlpx_b2 = (const float*)d_in[29];
    const float* mlpe_w1 = (const float*)d_in[30];
    const float* mlpe_b1 = (const float*)d_in[31];
    const float* mlpe_w2 = (const float*)d_in[32];
    const float* mlpe_b2 = (const float*)d_in[33];

    float* out_x = (float*)d_out;
    float* out_e = out_x + (size_t)BB * NN * DD;

    float* ws = (float*)d_ws;
    float* xn   = ws;                 // 98304
    float* Qb   = xn + 98304;
    float* Kx   = Qb + 98304;
    float* Vx   = Kx + 98304;
    float* xh   = Vx + 98304;
    float* accP = xh + 98304;         // 393216 (fallback, 4 splits)
    float* mP   = accP + 393216;      // 12288
    float* lP   = mP + 12288;         // 12288
    unsigned short* w1f  = (unsigned short*)(lP + 12288);   // 262144
    unsigned short* w2f  = w1f + 262144;                    // 262144
    unsigned short* WOef = w2f + 262144;                    // 65536
    unsigned short* Wqf  = WOef + 65536;                    // 65536
    unsigned short* Wkf  = Wqf + 65536;                     // 65536
    unsigned short* Wvf  = Wkf + 65536;                     // 65536
    float* accP3 = (float*)(Wvf + 65536);                   // 3*98304 = 294912
    float* mP3   = accP3 + 294912;                          // 9216
    float* lP3   = mP3 + 9216;                              // 9216

    const size_t NEED = 909312ull * 4 + 38453504ull * 2;
    bool mfma_path = ws_size >= NEED;

    dim3 blk(256);

    if (mfma_path) {
        k_prep_cvt<<<dim3(432), blk, 0, stream>>>(
            x, ln_x_g, ln_x_b, Wq_en, bq_en, Wk_ne, bk_ne, Wv_ne, bv_ne,
            xn, Qb, Kx, Vx,
            mlpe_w1, mlpe_w2, WOe_w, Wq_ne, Wk_en, Wv_en,
            w1f, w2f, WOef, Wqf, Wkf, Wvf);

        k_n2e_fused<<<dim3(NTILE3), dim3(512), 0, stream>>>(
            e, ln_e_g, ln_e_b, Wqf, bq_ne, Wkf, bk_en, Wvf, bv_en,
            Kx, Vx, Qb, WOef, WOe_b,
            ln_e2_g, ln_e2_b, w1f, mlpe_b1, w2f, mlpe_b2,
            out_e, accP3, mP3, lP3);

        k_x_epi3<<<dim3(BB * NN / 4), blk, 0, stream>>>(
            accP3, mP3, lP3, xn, WOx_w, WOx_b, ln_x2_g, ln_x2_b,
            mlpx_w1, mlpx_b1, mlpx_w2, mlpx_b2, out_x);
    } else {
        // fp32 fallback path
        k_node_prep<<<dim3(BB * NN / 8), blk, 0, stream>>>(
            x, ln_x_g, ln_x_b, Wq_en, bq_en, Wk_ne, bk_ne, Wv_ne, bv_ne,
            xn, Qb, Kx, Vx);

        k_n2e<<<dim3(BB * NN * (NN / 8)), blk, 0, stream>>>(
            e, ln_e_g, ln_e_b, Wq_ne, bq_ne, Kx, Vx, WOe_w, WOe_b, out_e);

        k_e2n_attn<<<dim3(BB * NN * SJ), blk, 0, stream>>>(
            e, ln_e_g, ln_e_b, Wk_en, bk_en, Wv_en, bv_en, Qb, accP, mP, lP);

        k_e2n_mergeN<<<dim3(BB * NN), blk, 0, stream>>>(accP, mP, lP, xh, SJ);

        k_x_epi<<<dim3(BB * NN / 8), blk, 0, stream>>>(
            xh, xn, WOx_w, WOx_b, ln_x2_g, ln_x2_b,
            mlpx_w1, mlpx_b1, mlpx_w2, mlpx_b2, out_x);

        k_e_mlp_f32<<<dim3(BB * NN * NN / 8), blk, 0, stream>>>(
            out_e, ln_e2_g, ln_e2_b, mlpe_w1, mlpe_b1, mlpe_w2, mlpe_b2);
    }
}